// Round 2
// baseline (566.700 us; speedup 1.0000x reference)
//
#include <hip/hip_runtime.h>

#define N_NODES 50000
#define E_EDGES 800000
#define E2      (2 * E_EDGES)
#define D_DIM   200
#define C_CLS   10
#define NB_BUCKET 196                        // buckets of 256 rows (r>>8)
#define BATCH     4096                       // edges per scatter block
#define NB_SCATTER ((E2 + BATCH - 1) / BATCH)        // 391
#define NB_CONV    ((N_NODES * D_DIM / 4 + 255) / 256) // 9766
#define CAP       12288                      // stage slots/bucket
#define NWIN      13                         // column windows: c>>12 (1.6 MB of W0h each)
#define RPW       8                          // rows per wave (group) in layer0
#define NGROUP    (N_NODES / RPW)            // 6250
#define NGROUP_ALL (NB_BUCKET * 32)          // 6272 (incl. tail bucket's empty groups)
#define NB_L0     ((NGROUP + 3) / 4)         // 1563

static __device__ __forceinline__ unsigned f2bf(float f) {
    unsigned u = __float_as_uint(f);
    return (u + 0x7FFFu + ((u >> 16) & 1u)) >> 16;     // RNE, low 16 bits
}
static __device__ __forceinline__ float bf_lo(unsigned u) {
    return __uint_as_float(u << 16);
}
static __device__ __forceinline__ float bf_hi(unsigned u) {
    return __uint_as_float(u & 0xFFFF0000u);
}

// ---------------------------------------------------------------------------
// Fused convert + scatter. UNCHANGED (proven).
// ---------------------------------------------------------------------------
__global__ __launch_bounds__(256) void convert_scatter_kernel(
        const float* __restrict__ W0, unsigned short* __restrict__ W0h,
        const int* __restrict__ rows0, const int* __restrict__ cols0,
        const float* __restrict__ vals0,
        const int* __restrict__ rows1, const int* __restrict__ cols1,
        const float* __restrict__ vals1,
        int* __restrict__ bcur,
        int2* __restrict__ stage) {
    __shared__ int cntL[NB_BUCKET];
    __shared__ int baseL[NB_BUCKET];
    __shared__ int offL[NB_BUCKET];
    __shared__ int2 recL[BATCH];            // 32 KB

    if (blockIdx.x >= NB_SCATTER) {
        int i = ((blockIdx.x - NB_SCATTER) * 256 + threadIdx.x) * 4;
        if (i < N_NODES * D_DIM) {
            float4 f = *(const float4*)(W0 + i);
            uint2 p;
            p.x = f2bf(f.x) | (f2bf(f.y) << 16);
            p.y = f2bf(f.z) | (f2bf(f.w) << 16);
            *(uint2*)(W0h + i) = p;
        }
        return;
    }

    const int tid = threadIdx.x;
    const int e0 = blockIdx.x * BATCH;

    for (int b = tid; b < NB_BUCKET; b += 256) cntL[b] = 0;
    __syncthreads();

#pragma unroll
    for (int k = 0; k < BATCH / 256; ++k) {
        int idx = k * 256 + tid;
        int e = e0 + idx;
        if (e < E2) {
            int r, c;
            float v;
            if (e < E_EDGES) {
                r = rows0[e]; c = cols0[e]; v = vals0[e];
            } else {
                int e1 = e - E_EDGES;
                r = rows1[e1]; c = cols1[e1]; v = vals1[e1];
            }
            recL[idx] = make_int2((int)((unsigned)r | ((unsigned)c << 16)),
                                  __float_as_int(v));
            atomicAdd(&cntL[r >> 8], 1);
        }
    }
    __syncthreads();

    for (int b = tid; b < NB_BUCKET; b += 256) {
        int c = cntL[b];
        baseL[b] = (c > 0) ? atomicAdd(&bcur[b], c) : 0;
        offL[b] = 0;
    }
    __syncthreads();

#pragma unroll
    for (int k = 0; k < BATCH / 256; ++k) {
        int idx = k * 256 + tid;
        int e = e0 + idx;
        if (e < E2) {
            int2 rec = recL[idx];
            int b = (int)(((unsigned)rec.x & 0xFFFFu) >> 8);
            int pos = baseL[b] + atomicAdd(&offL[b], 1);
            stage[(size_t)b * CAP + pos] = rec;
        }
    }
}

// ---------------------------------------------------------------------------
// Build CSR v3: dual layout.
//  (a) cv4/rowseg: per-row segments, window-sorted within row (for layer 1).
//  (b) cv8/gseg: per GROUP (8 rows) segments ordered (window, row-in-group),
//      records = (col | rig<<20, fp32 val), padded to x16 with zero records.
//      Layer 0 consumes these linearly -> window sweep with no branches.
// ---------------------------------------------------------------------------
__global__ __launch_bounds__(256) void build_csr_kernel(
        const int* __restrict__ bcur,
        const int2* __restrict__ stage,
        int* __restrict__ ticketA,
        int* __restrict__ ticketB,
        int2* __restrict__ rowseg,
        int2* __restrict__ gseg,
        unsigned* __restrict__ cv4,
        int2* __restrict__ cv8) {
    __shared__ int cntL[256 * NWIN];     // counts per (row_local, window) — never overwritten
    __shared__ int curA[256 * NWIN];     // cv4 cursors (row-major order)
    __shared__ int curB[256 * NWIN];     // cv8 cursors ((group, window, rig) order)
    __shared__ int mgw[32 * NWIN];       // per-(group, window) totals
    __shared__ int gw0[32 * NWIN];       // exclusive scan of mgw over windows within group
    __shared__ int gstartL[32];
    __shared__ int gtotL[32];
    __shared__ int ws4[4];
    __shared__ int sbaseA;
    const int b = blockIdx.x;
    const int tid = threadIdx.x;
    const int lane = tid & 63;
    const int wv = tid >> 6;

    for (int i = tid; i < 256 * NWIN; i += 256) cntL[i] = 0;
    __syncthreads();

    const int n = bcur[b];
    const int2* __restrict__ sp = stage + (size_t)b * CAP;
    for (int i = tid; i < n; i += 256) {
        unsigned u = (unsigned)sp[i].x;
        atomicAdd(&cntL[(u & 255u) * NWIN + (u >> 28)], 1);
    }
    __syncthreads();

    // ---- per-row totals + block scan -> cv4 cursors + rowseg ----
    int rowtot = 0;
#pragma unroll
    for (int k = 0; k < NWIN; ++k) rowtot += cntL[tid * NWIN + k];

    int v = rowtot;
#pragma unroll
    for (int off = 1; off < 64; off <<= 1) {
        int t = __shfl_up(v, off, 64);
        if (lane >= off) v += t;
    }
    if (lane == 63) ws4[wv] = v;
    __syncthreads();
    if (tid == 0) {
        int s = 0;
#pragma unroll
        for (int k = 0; k < 4; ++k) { int t = ws4[k]; ws4[k] = s; s += t; }
    }
    __syncthreads();
    v += ws4[wv];                              // inclusive over 256 rows

    if (tid == 255) sbaseA = atomicAdd(ticketA, v);
    __syncthreads();

    const int startA = sbaseA + v - rowtot;
    const int row = (b << 8) + tid;
    if (row < N_NODES) rowseg[row] = make_int2(startA, rowtot);
    {
        int c = startA;
#pragma unroll
        for (int k = 0; k < NWIN; ++k) { curA[tid * NWIN + k] = c; c += cntL[tid * NWIN + k]; }
    }

    // ---- group-window totals ----
    for (int i = tid; i < 32 * NWIN; i += 256) {
        int gl = i / NWIN, ww = i - gl * NWIN;
        int s = 0;
#pragma unroll
        for (int r = 0; r < 8; ++r) s += cntL[(gl * 8 + r) * NWIN + ww];
        mgw[i] = s;
    }
    __syncthreads();
    if (tid < 32) {
        int run = 0;
        for (int ww = 0; ww < NWIN; ++ww) { gw0[tid * NWIN + ww] = run; run += mgw[tid * NWIN + ww]; }
        gtotL[tid] = run;
    }
    __syncthreads();
    if (tid == 0) {
        int pre = 0;
        for (int gl = 0; gl < 32; ++gl) { gstartL[gl] = pre; pre += (gtotL[gl] + 15) & ~15; }
        int base = atomicAdd(ticketB, pre);
        for (int gl = 0; gl < 32; ++gl) gstartL[gl] += base;
    }
    __syncthreads();
    if (tid < 32) {
        int gs = gstartL[tid], gt = gtotL[tid];
        gseg[b * 32 + tid] = make_int2(gs, gt);
        int gp = (gt + 15) & ~15;
        for (int p = gt; p < gp; ++p) cv8[(size_t)gs + p] = make_int2(0, 0);  // zero pads
    }
    {
        // cv8 cursors: thread owns (group gl, rig r)
        int gl = tid >> 3, r = tid & 7;
        int cb[NWIN];
#pragma unroll
        for (int ww = 0; ww < NWIN; ++ww) {
            int s = 0;
            for (int r2 = 0; r2 < r; ++r2) s += cntL[(gl * 8 + r2) * NWIN + ww];
            cb[ww] = gstartL[gl] + gw0[gl * NWIN + ww] + s;
        }
#pragma unroll
        for (int ww = 0; ww < NWIN; ++ww) curB[tid * NWIN + ww] = cb[ww];
    }
    __syncthreads();

    // ---- placement: one pass, both layouts ----
    for (int i = tid; i < n; i += 256) {
        int2 rec = sp[i];
        unsigned u = (unsigned)rec.x;
        int cell = (int)((u & 255u) * NWIN + (u >> 28));
        int pA = atomicAdd(&curA[cell], 1);
        cv4[pA] = (u & 0xFFFF0000u) | f2bf(__int_as_float(rec.y));
        int pB = atomicAdd(&curB[cell], 1);
        cv8[pB] = make_int2((int)((u >> 16) | ((u & 7u) << 20)), rec.y);
    }
}

// ---------------------------------------------------------------------------
// Fused layer 0 v3: linear consumption of window-sorted group records.
// No data-dependent branches (trip count known) -> counted vmcnt, 8 gathers
// in flight, ping-pong record prefetch. Row dispatch via uniform scalar
// switch on rig (readfirstlane -> s_cbranch tree, SALU-parallel). Window
// sweep locality comes from all waves advancing through their window-sorted
// lists at the same rate (v2 proved FETCH 327->137 MB for this ordering).
// ---------------------------------------------------------------------------
__global__ __launch_bounds__(256) void spmm_layer0_fused_kernel(
        const int2* __restrict__ gseg,
        const int2* __restrict__ cv8,
        const unsigned short* __restrict__ W0h,
        const float* __restrict__ W1,
        const float* __restrict__ eps0,
        float* __restrict__ g) {
    __shared__ __align__(16) float W1Ts[C_CLS * D_DIM];   // [k][d] transposed
    for (int i = threadIdx.x; i < C_CLS * D_DIM; i += 256) {
        int k = i / D_DIM, d = i - k * D_DIM;
        W1Ts[i] = W1[d * C_CLS + k];
    }
    __syncthreads();

    const int lane = threadIdx.x & 63;
    const int vlane = (lane < 49) ? lane : 49;   // clamp: lanes 50-63 mirror 49 (no extra lines)
    const int wid = blockIdx.x * 4 + (threadIdx.x >> 6);
    const int n0 = wid * RPW;
    if (n0 >= N_NODES) return;                   // whole-wave exit only
    const float s0s = 0.1f * (1.0f + eps0[0]);
    const bool act = (lane < 50);
    const uint2* __restrict__ F = (const uint2*)W0h;

    float a[RPW][4];
#pragma unroll
    for (int j = 0; j < RPW; ++j) { a[j][0] = a[j][1] = a[j][2] = a[j][3] = 0.f; }

    int2 sg = gseg[wid];
    const int gstart = __builtin_amdgcn_readfirstlane(sg.x);
    const int gcnt   = __builtin_amdgcn_readfirstlane(sg.y);

    // accumulate one record: rig is a wave-uniform scalar -> scalar branch tree
    auto acc1 = [&](int s, uint2 q, float vv) {
        float f0 = bf_lo(q.x), f1 = bf_hi(q.x), f2 = bf_lo(q.y), f3 = bf_hi(q.y);
        switch (s >> 20) {
            case 0: a[0][0] += vv * f0; a[0][1] += vv * f1; a[0][2] += vv * f2; a[0][3] += vv * f3; break;
            case 1: a[1][0] += vv * f0; a[1][1] += vv * f1; a[1][2] += vv * f2; a[1][3] += vv * f3; break;
            case 2: a[2][0] += vv * f0; a[2][1] += vv * f1; a[2][2] += vv * f2; a[2][3] += vv * f3; break;
            case 3: a[3][0] += vv * f0; a[3][1] += vv * f1; a[3][2] += vv * f2; a[3][3] += vv * f3; break;
            case 4: a[4][0] += vv * f0; a[4][1] += vv * f1; a[4][2] += vv * f2; a[4][3] += vv * f3; break;
            case 5: a[5][0] += vv * f0; a[5][1] += vv * f1; a[5][2] += vv * f2; a[5][3] += vv * f3; break;
            case 6: a[6][0] += vv * f0; a[6][1] += vv * f1; a[6][2] += vv * f2; a[6][3] += vv * f3; break;
            case 7: a[7][0] += vv * f0; a[7][1] += vv * f1; a[7][2] += vv * f2; a[7][3] += vv * f3; break;
        }
    };
    // process 8 records: phase 1 issues all 8 gathers (no branches between),
    // phase 2 does the branchy accumulates on already-requested data.
    auto proc8 = [&](int4 x0, int4 x1, int4 x2, int4 x3) {
        int s0_ = __builtin_amdgcn_readfirstlane(x0.x);
        int s1_ = __builtin_amdgcn_readfirstlane(x0.z);
        int s2_ = __builtin_amdgcn_readfirstlane(x1.x);
        int s3_ = __builtin_amdgcn_readfirstlane(x1.z);
        int s4_ = __builtin_amdgcn_readfirstlane(x2.x);
        int s5_ = __builtin_amdgcn_readfirstlane(x2.z);
        int s6_ = __builtin_amdgcn_readfirstlane(x3.x);
        int s7_ = __builtin_amdgcn_readfirstlane(x3.z);
        uint2 q0 = F[(size_t)(s0_ & 0xFFFF) * 50 + vlane];
        uint2 q1 = F[(size_t)(s1_ & 0xFFFF) * 50 + vlane];
        uint2 q2 = F[(size_t)(s2_ & 0xFFFF) * 50 + vlane];
        uint2 q3 = F[(size_t)(s3_ & 0xFFFF) * 50 + vlane];
        uint2 q4 = F[(size_t)(s4_ & 0xFFFF) * 50 + vlane];
        uint2 q5 = F[(size_t)(s5_ & 0xFFFF) * 50 + vlane];
        uint2 q6 = F[(size_t)(s6_ & 0xFFFF) * 50 + vlane];
        uint2 q7 = F[(size_t)(s7_ & 0xFFFF) * 50 + vlane];
        acc1(s0_, q0, __int_as_float(x0.y));
        acc1(s1_, q1, __int_as_float(x0.w));
        acc1(s2_, q2, __int_as_float(x1.y));
        acc1(s3_, q3, __int_as_float(x1.w));
        acc1(s4_, q4, __int_as_float(x2.y));
        acc1(s5_, q5, __int_as_float(x2.w));
        acc1(s6_, q6, __int_as_float(x3.y));
        acc1(s7_, q7, __int_as_float(x3.w));
    };

    const int4* P = (const int4*)(cv8 + gstart);   // gstart multiple of 16 -> 16B aligned
    int4 A0 = P[0], A1 = P[1], A2 = P[2], A3 = P[3];
    for (int it = (gcnt + 15) >> 4; it > 0; --it) {
        int4 B0 = P[4], B1 = P[5], B2 = P[6], B3 = P[7];
        proc8(A0, A1, A2, A3);
        A0 = P[8]; A1 = P[9]; A2 = P[10]; A3 = P[11];   // prefetch next 16's first half
        proc8(B0, B1, B2, B3);
        P += 8;
    }

    // ---- epilogue: relu + @W1 (transposed, conflict-free float4 LDS reads) ----
    const float4* __restrict__ W1T4 = (const float4*)W1Ts;  // [C_CLS][50] float4
#pragma unroll
    for (int j = 0; j < RPW; ++j) {
        const int nn = n0 + j;
        float o[C_CLS];
#pragma unroll
        for (int k = 0; k < C_CLS; ++k) o[k] = 0.f;
        if (act) {
            uint2 wsv = F[(size_t)nn * 50 + lane];
            float b0 = fmaxf(a[j][0] + s0s * bf_lo(wsv.x), 0.f);
            float b1 = fmaxf(a[j][1] + s0s * bf_hi(wsv.x), 0.f);
            float b2 = fmaxf(a[j][2] + s0s * bf_lo(wsv.y), 0.f);
            float b3 = fmaxf(a[j][3] + s0s * bf_hi(wsv.y), 0.f);
#pragma unroll
            for (int k = 0; k < C_CLS; ++k) {
                float4 wv4 = W1T4[k * 50 + lane];
                o[k] = b0 * wv4.x + b1 * wv4.y + b2 * wv4.z + b3 * wv4.w;
            }
        }
#pragma unroll
        for (int k = 0; k < C_CLS; ++k) {
            for (int off2 = 32; off2 > 0; off2 >>= 1)
                o[k] += __shfl_xor(o[k], off2, 64);
        }
        if (lane == 0) {
            float* gp = g + (size_t)nn * C_CLS;
#pragma unroll
            for (int k = 0; k < C_CLS; ++k) gp[k] = o[k];
        }
    }
}

// ---------------------------------------------------------------------------
// Light layer 1 (UNCHANGED; uses rowseg + cv4, g is L2-resident).
// ---------------------------------------------------------------------------
__global__ __launch_bounds__(256) void spmm_layer1_light_kernel(
        const int2* __restrict__ rowseg,
        const unsigned* __restrict__ cv4,
        const float* __restrict__ g,
        const float* __restrict__ eps1,
        float* __restrict__ out) {
    const int lane = threadIdx.x & 63;
    const int n = __builtin_amdgcn_readfirstlane(blockIdx.x * 4 + (threadIdx.x >> 6));
    if (n >= N_NODES) return;
    const int grp = lane / 10;          // 0..5 active, 6 for lanes 60-63 (idle)
    const int d   = lane - grp * 10;    // 0..9
    const float s1 = 0.1f * (1.0f + eps1[0]);

    const int2 seg = rowseg[n];
    const int beg  = seg.x;
    const int endp = seg.x + seg.y;
    float acc = 0.f;

    for (int base = beg; base < endp; base += 12) {
        if (grp < 6) {
            int ea = base + grp;
            int eb = base + 6 + grp;
            unsigned pa = (ea < endp) ? cv4[ea] : 0u;
            unsigned pb = (eb < endp) ? cv4[eb] : 0u;
            if (ea < endp)
                acc += __uint_as_float(pa << 16) * g[(size_t)(pa >> 16) * C_CLS + d];
            if (eb < endp)
                acc += __uint_as_float(pb << 16) * g[(size_t)(pb >> 16) * C_CLS + d];
        }
    }

    float t;
    t = __shfl(acc, lane + 10, 64); if (lane < 50) acc += t;
    t = __shfl(acc, lane + 20, 64); if (lane < 30) acc += t;
    t = __shfl(acc, lane + 40, 64); if (lane < 10) acc += t;

    if (lane < 10) {
        out[(size_t)n * C_CLS + d] = acc + s1 * g[(size_t)n * C_CLS + d];
    }
}

// ---------------------------------------------------------------------------
extern "C" void kernel_launch(void* const* d_in, const int* in_sizes, int n_in,
                              void* d_out, int out_size, void* d_ws, size_t ws_size,
                              hipStream_t stream) {
    // setup_inputs order: x, rows0, cols0, vals0, rows1, cols1, vals1, W0, W1, eps0, eps1
    const int*   rows0 = (const int*)d_in[1];
    const int*   cols0 = (const int*)d_in[2];
    const float* vals0 = (const float*)d_in[3];
    const int*   rows1 = (const int*)d_in[4];
    const int*   cols1 = (const int*)d_in[5];
    const float* vals1 = (const float*)d_in[6];
    const float* W0    = (const float*)d_in[7];
    const float* W1    = (const float*)d_in[8];
    const float* eps0  = (const float*)d_in[9];
    const float* eps1  = (const float*)d_in[10];
    float* out = (float*)d_out;

    char* ws = (char*)d_ws;
    size_t off = 0;
    auto alloc = [&](size_t bytes) {
        void* p = ws + off;
        off += (bytes + 255) & ~(size_t)255;
        return p;
    };
    unsigned short* W0h = (unsigned short*)alloc((size_t)N_NODES * D_DIM * 2);  // 20 MB
    float* g      = (float*)alloc((size_t)N_NODES * C_CLS * 4);                 // 2 MB
    int2* rowseg  = (int2*)alloc((size_t)N_NODES * 8);                          // 400 KB
    int2* gseg    = (int2*)alloc((size_t)NGROUP_ALL * 8);                       // 50 KB
    int* bcur     = (int*)alloc((size_t)(NB_BUCKET + 2) * 4);                   // +2 tickets
    unsigned* cv4 = (unsigned*)alloc((size_t)E2 * 4);                           // 6.4 MB
    int2* cv8     = (int2*)alloc((size_t)(E2 + 16 * NGROUP_ALL + 32) * 8);      // 13.6 MB
    int2* stage   = (int2*)alloc((size_t)NB_BUCKET * CAP * 8);                  // 19.3 MB
    int* ticketA  = bcur + NB_BUCKET;
    int* ticketB  = bcur + NB_BUCKET + 1;
    (void)ws_size;

    hipMemsetAsync(bcur, 0, (size_t)(NB_BUCKET + 2) * 4, stream);
    convert_scatter_kernel<<<NB_SCATTER + NB_CONV, 256, 0, stream>>>(
        W0, W0h, rows0, cols0, vals0, rows1, cols1, vals1, bcur, stage);
    build_csr_kernel<<<NB_BUCKET, 256, 0, stream>>>(
        bcur, stage, ticketA, ticketB, rowseg, gseg, cv4, cv8);

    spmm_layer0_fused_kernel<<<NB_L0, 256, 0, stream>>>(
        gseg, cv8, W0h, W1, eps0, g);
    const int spmm1_grid = (N_NODES + 3) / 4;
    spmm_layer1_light_kernel<<<spmm1_grid, 256, 0, stream>>>(
        rowseg, cv4, g, eps1, out);
}

// Round 4
// 271.981 us; speedup vs baseline: 2.0836x; 2.0836x over previous
//
#include <hip/hip_runtime.h>

#define N_NODES 50000
#define E_EDGES 800000
#define E2      (2 * E_EDGES)
#define D_DIM   200
#define C_CLS   10
#define NB_BUCKET 196                        // buckets of 256 rows (r>>8)
#define BATCH     4096                       // edges per scatter block
#define NB_SCATTER ((E2 + BATCH - 1) / BATCH)        // 391
#define NB_CONV    ((N_NODES * D_DIM / 4 + 255) / 256) // 9766
#define CAP       12288                      // stage slots/bucket
#define NWIN      13                         // column windows: c>>12 (1.6 MB of W0h each)

static __device__ __forceinline__ unsigned f2bf(float f) {
    unsigned u = __float_as_uint(f);
    return (u + 0x7FFFu + ((u >> 16) & 1u)) >> 16;     // RNE, low 16 bits
}
static __device__ __forceinline__ float bf_lo(unsigned u) {
    return __uint_as_float(u << 16);
}
static __device__ __forceinline__ float bf_hi(unsigned u) {
    return __uint_as_float(u & 0xFFFF0000u);
}

// ---------------------------------------------------------------------------
// Fused convert + scatter. UNCHANGED (proven at 272 µs baseline).
// ---------------------------------------------------------------------------
__global__ __launch_bounds__(256) void convert_scatter_kernel(
        const float* __restrict__ W0, unsigned short* __restrict__ W0h,
        const int* __restrict__ rows0, const int* __restrict__ cols0,
        const float* __restrict__ vals0,
        const int* __restrict__ rows1, const int* __restrict__ cols1,
        const float* __restrict__ vals1,
        int* __restrict__ bcur,
        int2* __restrict__ stage) {
    __shared__ int cntL[NB_BUCKET];
    __shared__ int baseL[NB_BUCKET];
    __shared__ int offL[NB_BUCKET];
    __shared__ int2 recL[BATCH];            // 32 KB

    if (blockIdx.x >= NB_SCATTER) {
        // ---- convert path (streaming, no LDS use) ----
        int i = ((blockIdx.x - NB_SCATTER) * 256 + threadIdx.x) * 4;
        if (i < N_NODES * D_DIM) {
            float4 f = *(const float4*)(W0 + i);
            uint2 p;
            p.x = f2bf(f.x) | (f2bf(f.y) << 16);
            p.y = f2bf(f.z) | (f2bf(f.w) << 16);
            *(uint2*)(W0h + i) = p;
        }
        return;
    }

    // ---- scatter path ----
    const int tid = threadIdx.x;
    const int e0 = blockIdx.x * BATCH;

    for (int b = tid; b < NB_BUCKET; b += 256) cntL[b] = 0;
    __syncthreads();

#pragma unroll
    for (int k = 0; k < BATCH / 256; ++k) {
        int idx = k * 256 + tid;
        int e = e0 + idx;
        if (e < E2) {
            int r, c;
            float v;
            if (e < E_EDGES) {
                r = rows0[e]; c = cols0[e]; v = vals0[e];
            } else {
                int e1 = e - E_EDGES;
                r = rows1[e1]; c = cols1[e1]; v = vals1[e1];
            }
            recL[idx] = make_int2((int)((unsigned)r | ((unsigned)c << 16)),
                                  __float_as_int(v));
            atomicAdd(&cntL[r >> 8], 1);
        }
    }
    __syncthreads();

    for (int b = tid; b < NB_BUCKET; b += 256) {
        int c = cntL[b];
        baseL[b] = (c > 0) ? atomicAdd(&bcur[b], c) : 0;
        offL[b] = 0;
    }
    __syncthreads();

#pragma unroll
    for (int k = 0; k < BATCH / 256; ++k) {
        int idx = k * 256 + tid;
        int e = e0 + idx;
        if (e < E2) {
            int2 rec = recL[idx];
            int b = (int)(((unsigned)rec.x & 0xFFFFu) >> 8);
            int pos = baseL[b] + atomicAdd(&offL[b], 1);
            stage[(size_t)b * CAP + pos] = rec;
        }
    }
}

// ---------------------------------------------------------------------------
// Build CSR, two-key counting sort (row within bucket, column-window within
// row). Proven in round 1: delivers window-sorted per-row cv4 segments that
// cut layer-0 FETCH_SIZE 327 -> 137 MB. Per-row record order inside a window
// is arrival order; fp32 per-row sums reassociate (tolerated by absmax).
// ---------------------------------------------------------------------------
__global__ __launch_bounds__(256) void build_csr_kernel(
        const int* __restrict__ bcur,
        const int2* __restrict__ stage,
        int* __restrict__ ticket,
        int2* __restrict__ rowseg,
        unsigned* __restrict__ cv4) {
    __shared__ int hist[256 * NWIN];    // 13 KB: [row][window]
    __shared__ int ws4[4];
    __shared__ int sbase;
    const int b = blockIdx.x;
    const int tid = threadIdx.x;
    const int lane = tid & 63;
    const int w = tid >> 6;

    for (int i = tid; i < 256 * NWIN; i += 256) hist[i] = 0;
    __syncthreads();

    const int n = bcur[b];
    const int2* __restrict__ sp = stage + (size_t)b * CAP;
    for (int i = tid; i < n; i += 256) {
        unsigned u = (unsigned)sp[i].x;
        atomicAdd(&hist[(u & 255u) * NWIN + (u >> 28)], 1);   // u>>28 == c>>12, 0..12
    }
    __syncthreads();

    // Per-row total (thread tid owns row tid of this bucket).
    int rowtot = 0;
#pragma unroll
    for (int k = 0; k < NWIN; ++k) rowtot += hist[tid * NWIN + k];

    // Block inclusive scan of row totals.
    int v = rowtot;
#pragma unroll
    for (int off = 1; off < 64; off <<= 1) {
        int t = __shfl_up(v, off, 64);
        if (lane >= off) v += t;
    }
    if (lane == 63) ws4[w] = v;
    __syncthreads();
    if (tid == 0) {
        int s = 0;
#pragma unroll
        for (int k = 0; k < 4; ++k) { int t = ws4[k]; ws4[k] = s; s += t; }
    }
    __syncthreads();
    v += ws4[w];                              // inclusive over 256 rows

    if (tid == 255) sbase = atomicAdd(ticket, v);   // reserve [sbase, sbase+total)
    __syncthreads();

    const int start = sbase + v - rowtot;     // exclusive + base
    const int row = (b << 8) + tid;
    if (row < N_NODES) rowseg[row] = make_int2(start, rowtot);

    // Turn hist into global placement cursors (exclusive scan within row).
    int c = start;
#pragma unroll
    for (int k = 0; k < NWIN; ++k) {
        int t = hist[tid * NWIN + k];
        hist[tid * NWIN + k] = c;
        c += t;
    }
    __syncthreads();

    for (int i = tid; i < n; i += 256) {
        int2 rec = sp[i];
        unsigned u = (unsigned)rec.x;
        int pos = atomicAdd(&hist[(u & 255u) * NWIN + (u >> 28)], 1);
        cv4[pos] = (u & 0xFFFF0000u) | f2bf(__int_as_float(rec.y));
    }
}

// ---------------------------------------------------------------------------
// Fused layer 0: EXACT v0 hot loop (one wave per node, unroll-8, static
// accumulators, branch-free trip counts) — the structure that measured
// 100 µs / 33% VALUBusy / 28 VGPR. Only changes vs v0:
//  (1) cv4 segments are now window-sorted, so linear consumption sweeps
//      column windows 0..12 monotonically -> cross-wave L2 window locality
//      (round-1 measured FETCH 327->137 MB for this ordering).
//  (2) epilogue reads transposed W1 as float4 (bank-conflict-free; v0's
//      layout cost 1.5M LDS conflict cycles).
// ---------------------------------------------------------------------------
__global__ __launch_bounds__(256) void spmm_layer0_fused_kernel(
        const int2* __restrict__ rowseg,
        const unsigned* __restrict__ cv4,
        const unsigned short* __restrict__ W0h,
        const float* __restrict__ W1,
        const float* __restrict__ eps0,
        float* __restrict__ g) {
    __shared__ __align__(16) float W1Ts[C_CLS * D_DIM];   // [k][d] transposed
    for (int i = threadIdx.x; i < C_CLS * D_DIM; i += 256) {
        int k = i / D_DIM, d = i - k * D_DIM;
        W1Ts[i] = W1[d * C_CLS + k];
    }
    __syncthreads();

    const int lane = threadIdx.x & 63;
    const int n = __builtin_amdgcn_readfirstlane(blockIdx.x * 4 + (threadIdx.x >> 6));
    if (n >= N_NODES) return;
    const float s0 = 0.1f * (1.0f + eps0[0]);
    const bool act = (lane < 50);
    const uint2* __restrict__ F = (const uint2*)W0h;

    const int2 seg = rowseg[n];
    const int beg  = seg.x;
    const int endp = seg.x + seg.y;
    float a0 = 0.f, a1 = 0.f, a2 = 0.f, a3 = 0.f;

    int e = beg;
    for (; e + 8 <= endp; e += 8) {
        unsigned w0 = cv4[e],     w1 = cv4[e + 1], w2 = cv4[e + 2], w3 = cv4[e + 3];
        unsigned w4 = cv4[e + 4], w5 = cv4[e + 5], w6 = cv4[e + 6], w7 = cv4[e + 7];
        if (act) {
            uint2 u0 = F[(size_t)(w0 >> 16) * 50 + lane];
            uint2 u1 = F[(size_t)(w1 >> 16) * 50 + lane];
            uint2 u2 = F[(size_t)(w2 >> 16) * 50 + lane];
            uint2 u3 = F[(size_t)(w3 >> 16) * 50 + lane];
            uint2 u4 = F[(size_t)(w4 >> 16) * 50 + lane];
            uint2 u5 = F[(size_t)(w5 >> 16) * 50 + lane];
            uint2 u6 = F[(size_t)(w6 >> 16) * 50 + lane];
            uint2 u7 = F[(size_t)(w7 >> 16) * 50 + lane];
            float v0 = __uint_as_float(w0 << 16), v1 = __uint_as_float(w1 << 16);
            float v2 = __uint_as_float(w2 << 16), v3 = __uint_as_float(w3 << 16);
            float v4 = __uint_as_float(w4 << 16), v5 = __uint_as_float(w5 << 16);
            float v6 = __uint_as_float(w6 << 16), v7 = __uint_as_float(w7 << 16);
            a0 += v0 * bf_lo(u0.x) + v1 * bf_lo(u1.x) + v2 * bf_lo(u2.x) + v3 * bf_lo(u3.x)
                + v4 * bf_lo(u4.x) + v5 * bf_lo(u5.x) + v6 * bf_lo(u6.x) + v7 * bf_lo(u7.x);
            a1 += v0 * bf_hi(u0.x) + v1 * bf_hi(u1.x) + v2 * bf_hi(u2.x) + v3 * bf_hi(u3.x)
                + v4 * bf_hi(u4.x) + v5 * bf_hi(u5.x) + v6 * bf_hi(u6.x) + v7 * bf_hi(u7.x);
            a2 += v0 * bf_lo(u0.y) + v1 * bf_lo(u1.y) + v2 * bf_lo(u2.y) + v3 * bf_lo(u3.y)
                + v4 * bf_lo(u4.y) + v5 * bf_lo(u5.y) + v6 * bf_lo(u6.y) + v7 * bf_lo(u7.y);
            a3 += v0 * bf_hi(u0.y) + v1 * bf_hi(u1.y) + v2 * bf_hi(u2.y) + v3 * bf_hi(u3.y)
                + v4 * bf_hi(u4.y) + v5 * bf_hi(u5.y) + v6 * bf_hi(u6.y) + v7 * bf_hi(u7.y);
        }
    }
    for (; e + 4 <= endp; e += 4) {
        unsigned w0 = cv4[e], w1 = cv4[e + 1], w2 = cv4[e + 2], w3 = cv4[e + 3];
        if (act) {
            uint2 u0 = F[(size_t)(w0 >> 16) * 50 + lane];
            uint2 u1 = F[(size_t)(w1 >> 16) * 50 + lane];
            uint2 u2 = F[(size_t)(w2 >> 16) * 50 + lane];
            uint2 u3 = F[(size_t)(w3 >> 16) * 50 + lane];
            float v0 = __uint_as_float(w0 << 16), v1 = __uint_as_float(w1 << 16);
            float v2 = __uint_as_float(w2 << 16), v3 = __uint_as_float(w3 << 16);
            a0 += v0 * bf_lo(u0.x) + v1 * bf_lo(u1.x) + v2 * bf_lo(u2.x) + v3 * bf_lo(u3.x);
            a1 += v0 * bf_hi(u0.x) + v1 * bf_hi(u1.x) + v2 * bf_hi(u2.x) + v3 * bf_hi(u3.x);
            a2 += v0 * bf_lo(u0.y) + v1 * bf_lo(u1.y) + v2 * bf_lo(u2.y) + v3 * bf_lo(u3.y);
            a3 += v0 * bf_hi(u0.y) + v1 * bf_hi(u1.y) + v2 * bf_hi(u2.y) + v3 * bf_hi(u3.y);
        }
    }
    for (; e < endp; ++e) {
        unsigned w = cv4[e];
        if (act) {
            uint2 u = F[(size_t)(w >> 16) * 50 + lane];
            float v = __uint_as_float(w << 16);
            a0 += v * bf_lo(u.x);
            a1 += v * bf_hi(u.x);
            a2 += v * bf_lo(u.y);
            a3 += v * bf_hi(u.y);
        }
    }

    float o[C_CLS];
#pragma unroll
    for (int k = 0; k < C_CLS; ++k) o[k] = 0.f;

    const float4* __restrict__ W1T4 = (const float4*)W1Ts;  // [C_CLS][50] float4
    if (act) {
        uint2 w = F[(size_t)n * 50 + lane];
        a0 = fmaxf(a0 + s0 * bf_lo(w.x), 0.f);
        a1 = fmaxf(a1 + s0 * bf_hi(w.x), 0.f);
        a2 = fmaxf(a2 + s0 * bf_lo(w.y), 0.f);
        a3 = fmaxf(a3 + s0 * bf_hi(w.y), 0.f);
#pragma unroll
        for (int k = 0; k < C_CLS; ++k) {
            float4 wv = W1T4[k * 50 + lane];   // ds_read_b128, conflict-free
            o[k] = a0 * wv.x + a1 * wv.y + a2 * wv.z + a3 * wv.w;
        }
    }

#pragma unroll
    for (int k = 0; k < C_CLS; ++k) {
        for (int off = 32; off > 0; off >>= 1)
            o[k] += __shfl_xor(o[k], off, 64);
    }

    if (lane == 0) {
        float* gp = g + (size_t)n * C_CLS;
#pragma unroll
        for (int k = 0; k < C_CLS; ++k) gp[k] = o[k];
    }
}

// ---------------------------------------------------------------------------
// Light layer 1 (UNCHANGED; cv4 reorder only reassociates the fp32 sum, and
// its gathers hit the L2-resident 2 MB g array regardless of order).
// ---------------------------------------------------------------------------
__global__ __launch_bounds__(256) void spmm_layer1_light_kernel(
        const int2* __restrict__ rowseg,
        const unsigned* __restrict__ cv4,
        const float* __restrict__ g,
        const float* __restrict__ eps1,
        float* __restrict__ out) {
    const int lane = threadIdx.x & 63;
    const int n = __builtin_amdgcn_readfirstlane(blockIdx.x * 4 + (threadIdx.x >> 6));
    if (n >= N_NODES) return;
    const int grp = lane / 10;          // 0..5 active, 6 for lanes 60-63 (idle)
    const int d   = lane - grp * 10;    // 0..9
    const float s1 = 0.1f * (1.0f + eps1[0]);

    const int2 seg = rowseg[n];
    const int beg  = seg.x;
    const int endp = seg.x + seg.y;
    float acc = 0.f;

    for (int base = beg; base < endp; base += 12) {
        if (grp < 6) {
            int ea = base + grp;
            int eb = base + 6 + grp;
            unsigned pa = (ea < endp) ? cv4[ea] : 0u;
            unsigned pb = (eb < endp) ? cv4[eb] : 0u;
            if (ea < endp)
                acc += __uint_as_float(pa << 16) * g[(size_t)(pa >> 16) * C_CLS + d];
            if (eb < endp)
                acc += __uint_as_float(pb << 16) * g[(size_t)(pb >> 16) * C_CLS + d];
        }
    }

    float t;
    t = __shfl(acc, lane + 10, 64); if (lane < 50) acc += t;
    t = __shfl(acc, lane + 20, 64); if (lane < 30) acc += t;
    t = __shfl(acc, lane + 40, 64); if (lane < 10) acc += t;

    if (lane < 10) {
        out[(size_t)n * C_CLS + d] = acc + s1 * g[(size_t)n * C_CLS + d];
    }
}

// ---------------------------------------------------------------------------
extern "C" void kernel_launch(void* const* d_in, const int* in_sizes, int n_in,
                              void* d_out, int out_size, void* d_ws, size_t ws_size,
                              hipStream_t stream) {
    // setup_inputs order: x, rows0, cols0, vals0, rows1, cols1, vals1, W0, W1, eps0, eps1
    const int*   rows0 = (const int*)d_in[1];
    const int*   cols0 = (const int*)d_in[2];
    const float* vals0 = (const float*)d_in[3];
    const int*   rows1 = (const int*)d_in[4];
    const int*   cols1 = (const int*)d_in[5];
    const float* vals1 = (const float*)d_in[6];
    const float* W0    = (const float*)d_in[7];
    const float* W1    = (const float*)d_in[8];
    const float* eps0  = (const float*)d_in[9];
    const float* eps1  = (const float*)d_in[10];
    float* out = (float*)d_out;

    char* ws = (char*)d_ws;
    size_t off = 0;
    auto alloc = [&](size_t bytes) {
        void* p = ws + off;
        off += (bytes + 255) & ~(size_t)255;
        return p;
    };
    unsigned short* W0h = (unsigned short*)alloc((size_t)N_NODES * D_DIM * 2);  // 20 MB
    float* g      = (float*)alloc((size_t)N_NODES * C_CLS * 4);                 // 2 MB
    int2* rowseg  = (int2*)alloc((size_t)N_NODES * 8);                          // 400 KB
    int* bcur     = (int*)alloc((size_t)(NB_BUCKET + 1) * 4);                   // +ticket
    unsigned* cv4 = (unsigned*)alloc((size_t)E2 * 4);                           // 6.4 MB
    int2* stage   = (int2*)alloc((size_t)NB_BUCKET * CAP * 8);                  // 19.3 MB
    int* ticket   = bcur + NB_BUCKET;
    (void)ws_size;

    hipMemsetAsync(bcur, 0, (size_t)(NB_BUCKET + 1) * 4, stream);
    convert_scatter_kernel<<<NB_SCATTER + NB_CONV, 256, 0, stream>>>(
        W0, W0h, rows0, cols0, vals0, rows1, cols1, vals1, bcur, stage);
    build_csr_kernel<<<NB_BUCKET, 256, 0, stream>>>(bcur, stage, ticket, rowseg, cv4);

    const int spmm_grid = (N_NODES + 3) / 4;   // 4 waves/block, 1 wave per node
    spmm_layer0_fused_kernel<<<spmm_grid, 256, 0, stream>>>(
        rowseg, cv4, W0h, W1, eps0, g);
    spmm_layer1_light_kernel<<<spmm_grid, 256, 0, stream>>>(
        rowseg, cv4, g, eps1, out);
}